// Round 7
// baseline (164.102 us; speedup 1.0000x reference)
//
#include <hip/hip_runtime.h>
#include <math.h>

// ---------------------------------------------------------------------------
// HyperbolicInfoNCE on MI355X — Round 7: depth-2 software pipeline + fused
// fence-free finalize + vectorized convert.
//
// R6 post-mortem (58.8us gemm, 60us fixed overhead): prediction matched —
// ownership restructure worked. Remaining: (a) 176 regs/wave -> 2 waves/SIMD,
// compiler pipelines only ~1 load batch -> 44% idle; (b) convert+finalize+
// launch gaps = constant 60us.
// This round:
//   1. Explicit depth-2 pipeline over the 20 flattened (ct,kt) batches,
//      3 rotating fragment slots (96 VGPR) -> in-wave MLP x3 at unchanged
//      2 waves/SIMD.
//   2. Finalize fused into gemm via atomic-only protocol: all data written
//      with device-scope atomicAdd (coherent point), s_waitcnt(0) +
//      __syncthreads (which drains vmcnt anyway) before one counter
//      atomicAdd per block, last block reads via agent-scope atomic loads.
//      NO __threadfence (R5 lesson: per-block device fences = L2
//      writeback/invalidate storm, 147->355us).
//   3. Convert does 4 elems/thread (ushort4 stores) and zeroes rs/cp/dg/cnt.
// ---------------------------------------------------------------------------

#define BDIM   8192
#define K_IN   129
#define K_PAD  160      // 5 * 32
#define BK     32
#define NKT    (K_PAD / BK)   // 5
#define CTILES 4              // 64-col tiles per wave
#define NSTEP  (CTILES * NKT) // 20
#define NBLK   1024
#define KQ     (K_PAD / 4)    // 40

typedef __bf16  bf16x8 __attribute__((ext_vector_type(8)));
typedef float   f32x4  __attribute__((ext_vector_type(4)));

// ws layout (bytes): A, B, then rs | cp[4] | dg contiguous (zeroed together)
#define OFF_A    0u
#define OFF_B    (BDIM * K_PAD * 2u)                  // 2,621,440
#define OFF_RS   (2u * BDIM * K_PAD * 2u)             // 5,242,880
#define OFF_CP   (OFF_RS + BDIM * 4u)
#define OFF_DG   (OFF_CP + 4u * BDIM * 4u)
#define OFF_CNT  (OFF_DG + BDIM * 4u)

// ---- hardware transcendentals (v_sqrt_f32 / v_log_f32 / v_exp_f32) ----
__device__ __forceinline__ float fast_sqrt(float x) {
#if __has_builtin(__builtin_amdgcn_sqrtf)
    return __builtin_amdgcn_sqrtf(x);
#else
    return sqrtf(x);
#endif
}
__device__ __forceinline__ float fast_log2(float x) {
#if __has_builtin(__builtin_amdgcn_logf)
    return __builtin_amdgcn_logf(x);       // log base 2
#else
    return __log2f(x);
#endif
}
__device__ __forceinline__ float fast_exp2(float x) {
#if __has_builtin(__builtin_amdgcn_exp2f)
    return __builtin_amdgcn_exp2f(x);      // 2^x
#else
    extern "C" __device__ float __ocml_native_exp2_f32(float);
    return __ocml_native_exp2_f32(x);
#endif
}

__device__ __forceinline__ unsigned short f2bf_rne(float f) {
    unsigned int u = __float_as_uint(f);
    u += 0x7FFFu + ((u >> 16) & 1u);   // round-to-nearest-even
    return (unsigned short)(u >> 16);
}

// ---------------------------------------------------------------------------
// Kernel 1: fp32 -> bf16 (4 elems/thread, ushort4 stores), K zero-padded
// 129->160, Lorentz metric folded into A (negate column 0 of z1). Also
// zeroes rs + 4 col replicas + diag (6*BDIM contiguous floats) and cnt.
// ---------------------------------------------------------------------------
__global__ __launch_bounds__(256) void convert_kernel(
    const float* __restrict__ z1, const float* __restrict__ z2,
    unsigned short* __restrict__ A, unsigned short* __restrict__ B,
    float* __restrict__ zero6, unsigned int* __restrict__ cnt)
{
    int idx = blockIdx.x * 256 + threadIdx.x;    // [0, BDIM*KQ)
    if (idx == 0) *cnt = 0u;
    if (idx < 6 * BDIM) zero6[idx] = 0.f;
    if (idx >= BDIM * KQ) return;
    int r = idx / KQ;
    int k = (idx - r * KQ) * 4;                  // 0,4,...,156
    float va[4], vb[4];
    #pragma unroll
    for (int u = 0; u < 4; ++u) {
        int c = k + u;
        va[u] = 0.f; vb[u] = 0.f;
        if (c < K_IN) {
            va[u] = z1[r * K_IN + c];
            vb[u] = z2[r * K_IN + c];
            if (c == 0) va[u] = -va[u];          // Lorentz metric
        }
    }
    ushort4 ha, hb;
    ha.x = f2bf_rne(va[0]); ha.y = f2bf_rne(va[1]);
    ha.z = f2bf_rne(va[2]); ha.w = f2bf_rne(va[3]);
    hb.x = f2bf_rne(vb[0]); hb.y = f2bf_rne(vb[1]);
    hb.z = f2bf_rne(vb[2]); hb.w = f2bf_rne(vb[3]);
    *(ushort4*)&A[r * K_PAD + k] = ha;
    *(ushort4*)&B[r * K_PAD + k] = hb;
}

// ---------------------------------------------------------------------------
// Kernel 2: strip-GEMM, depth-2 pipelined fragment loads, fused acosh/exp
// epilogue, fused finalize in the last block to finish.
//   grid = 1024: bid = chunk*64 + strip  (consecutive blocks share B-chunk)
//   block: rows [strip*128,+128) x cols [chunk*512,+512); 4 waves 2x2;
//   wave: 64 rows x 4 col-tiles of 64x64 (4x4 MFMA 16x16x32 each).
//   fragment layouts (guide-verified, m89/m91):
//     A/B: elem [m=lane&15][k=(lane>>4)*8 + j]
//     C/D: elem [row=(lane>>4)*4 + reg][col=lane&15]
// ---------------------------------------------------------------------------
__global__ __launch_bounds__(256, 2) void gemm_epilogue_kernel(
    const unsigned short* __restrict__ A, const unsigned short* __restrict__ B,
    float* __restrict__ row_sum, float* __restrict__ col_part,
    float* __restrict__ diag, unsigned int* __restrict__ cnt,
    float* __restrict__ out)
{
    const int t    = threadIdx.x;
    const int lane = t & 63;
    const int wave = t >> 6;
    const int quad = lane >> 4;
    const int l16  = lane & 15;

    const int strip = blockIdx.x & 63;
    const int chunk = blockIdx.x >> 6;
    const int wr      = (wave >> 1) * 64;
    const int rowBase = strip * 128 + wr;
    const int colWave = chunk * 512 + (wave & 1) * 256;

    const unsigned short* Ab = A + (rowBase + l16) * K_PAD + quad * 8;
    const unsigned short* Bb = B + (colWave + l16) * K_PAD + quad * 8;
    float* colRep = col_part + (strip & 3) * BDIM;

    float rowp[4][4] = {};
    f32x4 acc[4][4] = {};
    bf16x8 afb[3][4], bfb[3][4];      // 3 rotating pipeline slots

    // prologue: batches 0,1 -> slots 0,1  (batch s: ct=s/5, kt=s%5)
    #pragma unroll
    for (int s = 0; s < 2; ++s) {
        const int ct = s / NKT, kt = s % NKT;
        #pragma unroll
        for (int i = 0; i < 4; ++i) {
            afb[s][i] = *(const bf16x8*)(Ab + i * 16 * K_PAD + kt * BK);
            bfb[s][i] = *(const bf16x8*)(Bb + (ct * 64 + i * 16) * K_PAD + kt * BK);
        }
    }

    #pragma unroll
    for (int s = 0; s < NSTEP; ++s) {
        // issue batch s+2 before consuming batch s
        if (s + 2 < NSTEP) {
            const int s2 = s + 2, ct2 = s2 / NKT, kt2 = s2 % NKT, sl2 = s2 % 3;
            #pragma unroll
            for (int i = 0; i < 4; ++i) {
                afb[sl2][i] = *(const bf16x8*)(Ab + i * 16 * K_PAD + kt2 * BK);
                bfb[sl2][i] = *(const bf16x8*)(Bb + (ct2 * 64 + i * 16) * K_PAD + kt2 * BK);
            }
        }
        const int slot = s % 3;
        #pragma unroll
        for (int i = 0; i < 4; ++i)
            #pragma unroll
            for (int j = 0; j < 4; ++j)
                acc[i][j] = __builtin_amdgcn_mfma_f32_16x16x32_bf16(
                                afb[slot][i], bfb[slot][j], acc[i][j], 0, 0, 0);

        // ---- tile finished: fused epilogue ----
        if (s % NKT == NKT - 1) {
            const int ct = s / NKT;
            const int colBase = colWave + ct * 64;
            const bool diagTile = (colBase == rowBase);
            float colp[4] = {0.f, 0.f, 0.f, 0.f};

            // u = x + sqrt(x^2-1), x = max(-inner, 1+1e-6)
            // exp(sims) = exp2(-14.2857142857 * log2(u))
            // sims      = -(ln2/0.07) * log2(u)
            #pragma unroll
            for (int i = 0; i < 4; ++i) {
                #pragma unroll
                for (int j = 0; j < 4; ++j) {
                    #pragma unroll
                    for (int reg = 0; reg < 4; ++reg) {
                        float inner = acc[i][j][reg];
                        float x = fmaxf(-inner, 1.000001f);
                        float sq = fast_sqrt(__builtin_fmaf(x, x, -1.0f));
                        float l2u = fast_log2(x + sq);
                        float e = fast_exp2(-14.285714285714286f * l2u);
                        rowp[i][reg] += e;
                        colp[j]      += e;
                        if (diagTile && i == j && (quad * 4 + reg) == l16) {
                            int R = rowBase + i * 16 + quad * 4 + reg;
                            atomicAdd(&diag[R], -9.902102579427789f * l2u);
                        }
                    }
                }
            }
            // col sums: reduce across quads, one atomic per col
            #pragma unroll
            for (int j = 0; j < 4; ++j) {
                float v = colp[j];
                v += __shfl_xor(v, 16);
                v += __shfl_xor(v, 32);
                if (quad == 0)
                    atomicAdd(&colRep[colBase + j * 16 + l16], v);
            }
            // reset accumulators for next tile
            #pragma unroll
            for (int i = 0; i < 4; ++i)
                #pragma unroll
                for (int j = 0; j < 4; ++j)
                    acc[i][j] = (f32x4){0.f, 0.f, 0.f, 0.f};
        }
    }

    // row sums (accumulated over all 4 col-tiles): reduce across quad lanes
    #pragma unroll
    for (int i = 0; i < 4; ++i) {
        #pragma unroll
        for (int reg = 0; reg < 4; ++reg) {
            float v = rowp[i][reg];
            v += __shfl_xor(v, 1);
            v += __shfl_xor(v, 2);
            v += __shfl_xor(v, 4);
            v += __shfl_xor(v, 8);
            if (l16 == 0)
                atomicAdd(&row_sum[rowBase + i * 16 + quad * 4 + reg], v);
        }
    }

    // ---- fused finalize: atomic-only protocol, NO fences ----
    // All data above was written via device-scope atomics (coherent point).
    // Drain this wave's outstanding ops, barrier, then one counter add.
    __builtin_amdgcn_s_waitcnt(0);
    __shared__ unsigned int lastFlag;
    __shared__ float part[4];
    __syncthreads();                  // also drains vmcnt per-wave
    if (t == 0) {
        unsigned int old = atomicAdd(cnt, 1u);
        lastFlag = (old == NBLK - 1u) ? 1u : 0u;
    }
    __syncthreads();
    if (lastFlag) {
        const float LN2_HALF = 0.34657359027997264f;  // 0.5 * ln2
        float a = 0.f;
        for (int b = t; b < BDIM; b += 256) {
            float r = __hip_atomic_load(&row_sum[b], __ATOMIC_RELAXED,
                                        __HIP_MEMORY_SCOPE_AGENT);
            float c0 = __hip_atomic_load(&col_part[b], __ATOMIC_RELAXED,
                                         __HIP_MEMORY_SCOPE_AGENT);
            float c1 = __hip_atomic_load(&col_part[b + BDIM], __ATOMIC_RELAXED,
                                         __HIP_MEMORY_SCOPE_AGENT);
            float c2 = __hip_atomic_load(&col_part[b + 2 * BDIM], __ATOMIC_RELAXED,
                                         __HIP_MEMORY_SCOPE_AGENT);
            float c3 = __hip_atomic_load(&col_part[b + 3 * BDIM], __ATOMIC_RELAXED,
                                         __HIP_MEMORY_SCOPE_AGENT);
            float d = __hip_atomic_load(&diag[b], __ATOMIC_RELAXED,
                                        __HIP_MEMORY_SCOPE_AGENT);
            a += LN2_HALF * (fast_log2(r) + fast_log2(c0 + c1 + c2 + c3)) - d;
        }
        #pragma unroll
        for (int m = 1; m < 64; m <<= 1) a += __shfl_xor(a, m);
        if (lane == 0) part[wave] = a;
        __syncthreads();
        if (t == 0)
            out[0] = (part[0] + part[1] + part[2] + part[3])
                     * (1.0f / (float)BDIM);
    }
}

// ---------------------------------------------------------------------------
extern "C" void kernel_launch(void* const* d_in, const int* in_sizes, int n_in,
                              void* d_out, int out_size, void* d_ws, size_t ws_size,
                              hipStream_t stream)
{
    const float* z1 = (const float*)d_in[0];
    const float* z2 = (const float*)d_in[1];
    float* out = (float*)d_out;

    char* ws = (char*)d_ws;
    unsigned short* A  = (unsigned short*)(ws + OFF_A);
    unsigned short* B  = (unsigned short*)(ws + OFF_B);
    float* row_sum     = (float*)(ws + OFF_RS);
    float* col_part    = (float*)(ws + OFF_CP);
    float* diag        = (float*)(ws + OFF_DG);
    unsigned int* cnt  = (unsigned int*)(ws + OFF_CNT);

    convert_kernel<<<(BDIM * KQ + 255) / 256, 256, 0, stream>>>(
        z1, z2, A, B, row_sum /* rs|cp|dg contiguous */, cnt);

    gemm_epilogue_kernel<<<NBLK, 256, 0, stream>>>(
        A, B, row_sum, col_part, diag, cnt, out);
}